// Round 7
// baseline (296.506 us; speedup 1.0000x reference)
//
#include <hip/hip_runtime.h>

// B=4, T=2048, C=1024, H=16, HS=64
typedef __attribute__((ext_vector_type(8))) short v8s;
typedef __attribute__((ext_vector_type(4))) short v4s;
typedef __attribute__((ext_vector_type(4))) float v4f;

static __device__ __forceinline__ short f2bf(float f) {
  union { float f; unsigned u; } c; c.f = f;
  unsigned r = c.u + 0x7fffu + ((c.u >> 16) & 1u);
  return (short)(r >> 16);
}

// round-half-up pack of two f32 -> bf16x2
static __device__ __forceinline__ unsigned pk_bf16(float a, float b) {
  union { float f; unsigned u; } ca, cb; ca.f = a; cb.f = b;
  return ((ca.u + 0x8000u) >> 16) | ((cb.u + 0x8000u) & 0xffff0000u);
}

#if __has_builtin(__builtin_amdgcn_exp2f)
#define EXP2(x) __builtin_amdgcn_exp2f(x)
#else
#define EXP2(x) exp2f(x)
#endif

#define GLDS(gp, lp) __builtin_amdgcn_global_load_lds( \
    (const __attribute__((address_space(1))) void*)(gp), \
    (__attribute__((address_space(3))) void*)(lp), 16, 0, 0)

// ---------------- fused prep: cast x, cast Wo, build Wt ----------------
// blocks [0,8192): cast x (f32->bf16, 1024 elems/block)
// blocks [8192,9216): cast Wo
// blocks [9216,9984): transpose-cast Wq/Wk/Wv -> Wt [3072][1024]

__global__ __launch_bounds__(256) void prep(const float* __restrict__ x,
                                            const float* __restrict__ Wq,
                                            const float* __restrict__ Wk,
                                            const float* __restrict__ Wv,
                                            const float* __restrict__ Wo,
                                            short* __restrict__ Xb,
                                            short* __restrict__ Wot,
                                            short* __restrict__ Wt) {
  __shared__ float tile[64][65];
  int blk = blockIdx.x;
  int tid = threadIdx.x;
  if (blk < 9216) {
    const float* src = (blk < 8192) ? x : Wo;
    short* dst = (blk < 8192) ? Xb : Wot;
    int bb = (blk < 8192) ? blk : (blk - 8192);
    int idx = (bb * 256 + tid) * 4;
    float4 v = *(const float4*)(src + idx);
    v4s o; o.x = f2bf(v.x); o.y = f2bf(v.y); o.z = f2bf(v.z); o.w = f2bf(v.w);
    *(v4s*)(dst + idx) = o;
    return;
  }
  int wblk = blk - 9216;                // 768 = 3*16*16
  int sel = wblk >> 8, rest = wblk & 255;
  int h = rest >> 4, kt = rest & 15;
  const float* W = (sel == 0) ? Wq : ((sel == 1) ? Wk : Wv);
  int k0 = kt * 64;
  for (int i = 0; i < 4; ++i) {
    int c = i * 256 + tid;              // 1024 float4 chunks
    int row = c >> 4, c4 = (c & 15) * 4;
    float4 v = *(const float4*)(W + (size_t)h * 65536 + (size_t)(k0 + row) * 64 + c4);
    tile[row][c4 + 0] = v.x; tile[row][c4 + 1] = v.y;
    tile[row][c4 + 2] = v.z; tile[row][c4 + 3] = v.w;
  }
  __syncthreads();
  for (int i = 0; i < 2; ++i) {
    int c = i * 256 + tid;              // 512 v8s chunks
    int d = c >> 3, k8 = (c & 7) * 8;
    v8s o;
    for (int j = 0; j < 8; ++j) o[j] = f2bf(tile[k8 + j][d]);
    *(v8s*)(Wt + (size_t)(sel * 1024 + h * 64 + d) * 1024 + k0 + k8) = o;
  }
}

// ---------------- QKV GEMM: [8192x1024] @ Wt^T (Wt is [3072][1024]) ----------------
// Q/K blocks (n0<2048) write [bh][t][64]. V blocks (n0>=2048) swap MFMA operands
// (computing C^T at zero cost) and store directly into Vt [bh][d][t] — this fuses
// the old transpose_v kernel away.

__global__ __launch_bounds__(256) void gemm_qkv(const short* __restrict__ Xb,
                                                const short* __restrict__ Wt,
                                                short* __restrict__ Qo,
                                                short* __restrict__ Ko,
                                                short* __restrict__ Vt) {
  __shared__ short lA[128 * 32];
  __shared__ short lB[128 * 32];
  const int tid = threadIdx.x;
  const int lane = tid & 63, quad = lane >> 4, l16 = lane & 15;
  const int wave = tid >> 6;
  const int m0 = blockIdx.x * 128, n0 = blockIdx.y * 128;
  const int wm = (wave >> 1) * 64, wn = (wave & 1) * 64;
  const bool vblk = (n0 >= 2048);       // block-uniform
  v4f acc[4][4];
  for (int i = 0; i < 4; ++i)
    for (int j = 0; j < 4; ++j) acc[i][j] = (v4f){0.f, 0.f, 0.f, 0.f};

  for (int k0 = 0; k0 < 1024; k0 += 32) {
    __syncthreads();
    for (int i = 0; i < 2; ++i) {
      int c = i * 256 + tid;            // 512 16B chunks per tile
      int row = c >> 2, kc = c & 3;
      GLDS(Xb + (size_t)(m0 + row) * 1024 + k0 + kc * 8, lA + c * 8);
      GLDS(Wt + (size_t)(n0 + row) * 1024 + k0 + kc * 8, lB + c * 8);
    }
    __syncthreads();
    v8s a[4], b[4];
    for (int mt = 0; mt < 4; ++mt) a[mt] = *(const v8s*)&lA[(wm + mt * 16 + l16) * 32 + quad * 8];
    for (int nt = 0; nt < 4; ++nt) b[nt] = *(const v8s*)&lB[(wn + nt * 16 + l16) * 32 + quad * 8];
    if (!vblk) {
      for (int mt = 0; mt < 4; ++mt)
        for (int nt = 0; nt < 4; ++nt)
          acc[mt][nt] = __builtin_amdgcn_mfma_f32_16x16x32_bf16(a[mt], b[nt], acc[mt][nt], 0, 0, 0);
    } else {
      for (int mt = 0; mt < 4; ++mt)
        for (int nt = 0; nt < 4; ++nt)
          acc[mt][nt] = __builtin_amdgcn_mfma_f32_16x16x32_bf16(b[nt], a[mt], acc[mt][nt], 0, 0, 0);
    }
  }

  if (!vblk) {
    // Q/K epilogue: scatter into [bh][T][64]
    short* obase = (n0 < 1024) ? Qo : Ko;
    for (int nt = 0; nt < 4; ++nt) {
      int n = n0 + wn + nt * 16 + l16;
      int hd = n & 1023;
      int h = hd >> 6, d = hd & 63;
      for (int mt = 0; mt < 4; ++mt)
        for (int r = 0; r < 4; ++r) {
          int m = m0 + wm + mt * 16 + quad * 4 + r;
          int b_ = m >> 11, t = m & 2047;
          obase[(size_t)((b_ * 16 + h) * 2048 + t) * 64 + d] = f2bf(acc[mt][nt][r]);
        }
    }
  } else {
    // V epilogue (acc holds C^T): rows = n (head dim), cols = m (time)
    for (int nt = 0; nt < 4; ++nt)
      for (int r = 0; r < 4; ++r) {
        int n = n0 + wn + nt * 16 + quad * 4 + r;
        int hd = n & 1023;
        int h = hd >> 6, d = hd & 63;
        for (int mt = 0; mt < 4; ++mt) {
          int m = m0 + wm + mt * 16 + l16;
          int b_ = m >> 11, t = m & 2047;
          Vt[(size_t)((b_ * 16 + h) * 64 + d) * 2048 + t] = f2bf(acc[mt][nt][r]);
        }
      }
  }
}

// ---------------- flash attention (S^T form, LDS-staged K/V, 32 q-rows/wave) --------
// grid: 512 blocks; bh = blockIdx%64 (same bh -> same XCD), pair pr = blockIdx/64 in [0,8).
// block 256 = 4 waves x 32 q-rows = 128 q-rows; phases c=pr then c=15-pr (chunks of 128)
// -> 36 key-tiles per block, identical for every block.
// Each wave handles TWO 16-row q-subsets, so the staged K/V fragments (ds_read_b128)
// are reused across 32 q-rows. Softmax: fixed-max exp2, sum deferred to epilogue.

__global__ __launch_bounds__(256, 2) void attn(const short* __restrict__ Q,
                                               const short* __restrict__ K,
                                               const short* __restrict__ Vt,
                                               short* __restrict__ AO) {
  __shared__ short lK[64 * 64];         // 8 KB staged K tile (swizzled)
  __shared__ short lV[64 * 64];         // 8 KB staged V^T tile (swizzled)
  __shared__ short lP[4 * 32 * 72];     // 18 KB P round-trip (per-wave 32x72 regions)
  const int tid = threadIdx.x;
  const int w = tid >> 6, lane = tid & 63, quad = lane >> 4, l16 = lane & 15;
  const int bh = blockIdx.x & 63, pr = blockIdx.x >> 6;
  const float kexp = 0.18033688011112042f;  // (1/8) * log2(e)
  const unsigned psel = 0x07060302u;        // v_perm: {hi16(b), hi16(a)}
  short* pw = lP + w * (32 * 72);
  const size_t qkbase = (size_t)bh * 2048 * 64;
  const size_t vtbase = (size_t)bh * 64 * 2048;
  const int b_ = bh >> 4, h = bh & 15;

  // staging map: thread handles chunks c0=tid, c1=tid+256 of each tile
  const int r0 = tid >> 3, cp = tid & 7;
  const int cl0 = cp ^ (r0 & 7);
  const int r1 = r0 + 32;
  const int cl1 = cp ^ (r1 & 7);

  // fragment LDS offsets (shorts): row*64 + (col8log ^ (l16&7))*8
  const int swz = l16 & 7;
  const int ph0 = (quad ^ swz) * 8;           // col8log = quad   (k 0..31)
  const int ph1 = ((quad + 4) ^ swz) * 8;     // col8log = quad+4 (k 32..63)

  for (int phase = 0; phase < 2; ++phase) {
    const int c = phase ? (15 - pr) : pr;
    const int qc = c * 128 + w * 32;          // this wave's first q-row

    // Q fragments (B-operand of S^T): B[k=d][n=qrow], two 16-row subsets
    v8s bQ[2][2];
#pragma unroll
    for (int qs = 0; qs < 2; ++qs) {
      const short* qb = Q + qkbase + (size_t)(qc + qs * 16 + l16) * 64 + quad * 8;
      bQ[qs][0] = *(const v8s*)(qb);
      bQ[qs][1] = *(const v8s*)(qb + 32);
    }
    v4f accO[2][4];
#pragma unroll
    for (int qs = 0; qs < 2; ++qs)
      for (int g = 0; g < 4; ++g) accO[qs][g] = (v4f){0.f, 0.f, 0.f, 0.f};
    float lrun[2] = {0.f, 0.f};

    const int nst = 2 * c + 2;                // 64-key tiles covering the 128-row chunk
    for (int kt = 0; kt < nst; ++kt) {
      const int kb = kt * 64;
      __syncthreads();                  // prior stage done reading lK/lV
      // ---- stage K tile rows kb..kb+63 and V^T tile cols kb..kb+63 ----
      GLDS(K + qkbase + (size_t)(kb + r0) * 64 + cl0 * 8, lK + tid * 8);
      GLDS(K + qkbase + (size_t)(kb + r1) * 64 + cl1 * 8, lK + tid * 8 + 2048);
      GLDS(Vt + vtbase + (size_t)r0 * 2048 + kb + cl0 * 8, lV + tid * 8);
      GLDS(Vt + vtbase + (size_t)r1 * 2048 + kb + cl1 * 8, lV + tid * 8 + 2048);
      __syncthreads();                  // staged data visible

      const bool act0 = kb < qc + 16;   // qs=0 has unmasked keys this stage
      const bool act1 = kb < qc + 32;   // qs=1 (superset of act0)
      if (!act1) continue;              // wave-uniform; barriers already passed

      // ---- K fragments (shared by both q-subsets) ----
      v8s aK[4][2];
#pragma unroll
      for (int mt = 0; mt < 4; ++mt) {
        const short* kr = lK + (mt * 16 + l16) * 64;
        aK[mt][0] = *(const v8s*)(kr + ph0);
        aK[mt][1] = *(const v8s*)(kr + ph1);
      }
      // ---- per q-subset: S^T, mask, exp, pack into LDS ----
#pragma unroll
      for (int qs = 0; qs < 2; ++qs) {
        if (qs == 0 ? !act0 : false) continue;
        const int rbase = qc + qs * 16;
        v4f sT[4];
#pragma unroll
        for (int mt = 0; mt < 4; ++mt) {
          v4f t = (v4f){0.f, 0.f, 0.f, 0.f};
          t = __builtin_amdgcn_mfma_f32_16x16x32_bf16(aK[mt][0], bQ[qs][0], t, 0, 0, 0);
          t = __builtin_amdgcn_mfma_f32_16x16x32_bf16(aK[mt][1], bQ[qs][1], t, 0, 0, 0);
          sT[mt] = t;
        }
        if (kb + 63 >= rbase) {         // diagonal-overlap: element mask
          const int kq = kb + quad * 4 - (rbase + l16);
#pragma unroll
          for (int mt = 0; mt < 4; ++mt)
#pragma unroll
            for (int r = 0; r < 4; ++r)
              if (kq + mt * 16 + r > 0) sT[mt][r] = -__builtin_inff();
        }
        float ls = lrun[qs];
#pragma unroll
        for (int mt = 0; mt < 4; ++mt) {
          float p0 = EXP2(sT[mt][0] * kexp);
          float p1 = EXP2(sT[mt][1] * kexp);
          float p2 = EXP2(sT[mt][2] * kexp);
          float p3 = EXP2(sT[mt][3] * kexp);
          ls += (p0 + p1) + (p2 + p3);
          int2 dw;
          dw.x = (int)__builtin_amdgcn_perm(__float_as_uint(p1), __float_as_uint(p0), psel);
          dw.y = (int)__builtin_amdgcn_perm(__float_as_uint(p3), __float_as_uint(p2), psel);
          *(int2*)&pw[(qs * 16 + l16) * 72 + mt * 16 + quad * 4] = dw;
        }
        lrun[qs] = ls;
      }
      // ---- V fragments (shared) + PV per q-subset ----
      v8s aV[4][2];
#pragma unroll
      for (int g = 0; g < 4; ++g) {
        const short* vr = lV + (g * 16 + l16) * 64;
        aV[g][0] = *(const v8s*)(vr + ph0);
        aV[g][1] = *(const v8s*)(vr + ph1);
      }
#pragma unroll
      for (int qs = 0; qs < 2; ++qs) {
        if (qs == 0 ? !act0 : false) continue;
        v8s bP0 = *(const v8s*)&pw[(qs * 16 + l16) * 72 + quad * 8];
        v8s bP1 = *(const v8s*)&pw[(qs * 16 + l16) * 72 + 32 + quad * 8];
#pragma unroll
        for (int g = 0; g < 4; ++g) {
          accO[qs][g] = __builtin_amdgcn_mfma_f32_16x16x32_bf16(aV[g][0], bP0, accO[qs][g], 0, 0, 0);
          accO[qs][g] = __builtin_amdgcn_mfma_f32_16x16x32_bf16(aV[g][1], bP1, accO[qs][g], 0, 0, 0);
        }
      }
    }

    // ---- epilogue: finish row-sums (across the 4 quads), normalize, store O^T ----
#pragma unroll
    for (int qs = 0; qs < 2; ++qs) {
      float ls = lrun[qs];
      ls += __shfl_xor(ls, 16);
      ls += __shfl_xor(ls, 32);
      float inv = __builtin_amdgcn_rcpf(ls);
      int t = qc + qs * 16 + l16;
      short* ao = AO + ((size_t)(b_ * 2048 + t)) * 1024 + h * 64 + quad * 4;
#pragma unroll
      for (int g = 0; g < 4; ++g) {
        int2 dw;
        dw.x = (int)pk_bf16(accO[qs][g][0] * inv, accO[qs][g][1] * inv);
        dw.y = (int)pk_bf16(accO[qs][g][2] * inv, accO[qs][g][3] * inv);
        *(int2*)(ao + g * 16) = dw;     // d = g*16 + quad*4 + {0..3}
      }
    }
  }
}

// ---------------- output projection: out = AO @ Wo^T + bo (fp32 out) ----------------

__global__ __launch_bounds__(256) void gemm_out(const short* __restrict__ AO,
                                                const short* __restrict__ Wot,
                                                const float* __restrict__ bo,
                                                float* __restrict__ out) {
  __shared__ short lA[128 * 32];
  __shared__ short lB[128 * 32];
  const int tid = threadIdx.x;
  const int lane = tid & 63, quad = lane >> 4, l16 = lane & 15;
  const int wave = tid >> 6;
  const int m0 = blockIdx.x * 128, n0 = blockIdx.y * 128;
  const int wm = (wave >> 1) * 64, wn = (wave & 1) * 64;
  v4f acc[4][4];
  for (int i = 0; i < 4; ++i)
    for (int j = 0; j < 4; ++j) acc[i][j] = (v4f){0.f, 0.f, 0.f, 0.f};

  for (int k0 = 0; k0 < 1024; k0 += 32) {
    __syncthreads();
    for (int i = 0; i < 2; ++i) {
      int c = i * 256 + tid;
      int row = c >> 2, kc = c & 3;
      GLDS(AO + (size_t)(m0 + row) * 1024 + k0 + kc * 8, lA + c * 8);
      GLDS(Wot + (size_t)(n0 + row) * 1024 + k0 + kc * 8, lB + c * 8);
    }
    __syncthreads();
    v8s a[4], b[4];
    for (int mt = 0; mt < 4; ++mt) a[mt] = *(const v8s*)&lA[(wm + mt * 16 + l16) * 32 + quad * 8];
    for (int nt = 0; nt < 4; ++nt) b[nt] = *(const v8s*)&lB[(wn + nt * 16 + l16) * 32 + quad * 8];
    for (int mt = 0; mt < 4; ++mt)
      for (int nt = 0; nt < 4; ++nt)
        acc[mt][nt] = __builtin_amdgcn_mfma_f32_16x16x32_bf16(a[mt], b[nt], acc[mt][nt], 0, 0, 0);
  }

  for (int nt = 0; nt < 4; ++nt) {
    int n = n0 + wn + nt * 16 + l16;
    float bias = bo[n];
    for (int mt = 0; mt < 4; ++mt)
      for (int r = 0; r < 4; ++r) {
        int m = m0 + wm + mt * 16 + quad * 4 + r;
        out[(size_t)m * 1024 + n] = acc[mt][nt][r] + bias;
      }
  }
}

// ---------------- launch ----------------

extern "C" void kernel_launch(void* const* d_in, const int* in_sizes, int n_in,
                              void* d_out, int out_size, void* d_ws, size_t ws_size,
                              hipStream_t stream) {
  const float* x  = (const float*)d_in[0];
  const float* Wq = (const float*)d_in[1];
  const float* Wk = (const float*)d_in[2];
  const float* Wv = (const float*)d_in[3];
  const float* Wo = (const float*)d_in[4];
  const float* bo = (const float*)d_in[5];
  float* out = (float*)d_out;
  char* ws = (char*)d_ws;

  short* Xb  = (short*)(ws);                          // 16 MB (reused as AO after QKV GEMM)
  short* Wt  = (short*)(ws + (16u << 20));            // 6 MB
  short* Wot = (short*)(ws + (22u << 20));            // 2 MB
  short* Q   = (short*)(ws + (24u << 20));            // 16 MB
  short* K   = (short*)(ws + (40u << 20));            // 16 MB
  short* Vt  = (short*)(ws + (56u << 20));            // 16 MB  -> total 72 MB

  prep<<<9984, 256, 0, stream>>>(x, Wq, Wk, Wv, Wo, Xb, Wot, Wt);
  gemm_qkv<<<dim3(64, 24), 256, 0, stream>>>(Xb, Wt, Q, K, Vt);
  attn<<<dim3(512), 256, 0, stream>>>(Q, K, Vt, Xb);  // AO aliases Xb
  gemm_out<<<dim3(64, 8), 256, 0, stream>>>(Xb, Wot, bo, out);
}